// Round 1
// baseline (521.964 us; speedup 1.0000x reference)
//
#include <hip/hip_runtime.h>
#include <hip/hip_bf16.h>

typedef unsigned short u16;
typedef __bf16 bf16x8 __attribute__((ext_vector_type(8)));
typedef float f32x4 __attribute__((ext_vector_type(4)));

#define LDA 136   // 128 + 8 bf16 pad: keeps 16B alignment, 2-way (free) bank conflict

__device__ __forceinline__ u16 f2b(float f) {
  unsigned u = __builtin_bit_cast(unsigned, f);
  u = u + 0x7FFFu + ((u >> 16) & 1u);   // RNE
  return (u16)(u >> 16);
}
__device__ __forceinline__ float b2f(u16 h) {
  unsigned u = ((unsigned)h) << 16;
  return __builtin_bit_cast(float, u);
}
__device__ __forceinline__ bf16x8 zero8() {
  union { int4 i; bf16x8 v; } u;
  u.i = make_int4(0, 0, 0, 0);
  return u.v;
}
__device__ __forceinline__ f32x4 mfma16(bf16x8 a, bf16x8 b, f32x4 c) {
  return __builtin_amdgcn_mfma_f32_16x16x32_bf16(a, b, c, 0, 0, 0);
}

// ---------------- weight prep: transpose + fp32->bf16 into workspace ----------
// ws layout (u16 elements):
//   WqT [128][128] @ 0        : WqT[h*16+e][d] = Wq[h][d][e]
//   WkT [128][128] @ 16384
//   WvT [128][128] @ 32768
//   WoT [128][128] @ 49152    : WoT[n][k] = Wo[k][n]
//   W1T [512][128] @ 65536    : W1T[n][k] = W1[k][n]
//   W2T [128][512] @ 131072   : W2T[n][k] = W2[k][n]
__global__ void prep_kernel(const float* __restrict__ Wq, const float* __restrict__ Wk,
                            const float* __restrict__ Wv, const float* __restrict__ Wo,
                            const float* __restrict__ W1, const float* __restrict__ W2,
                            u16* __restrict__ o) {
  int i = blockIdx.x * 256 + threadIdx.x;
  if (i >= 196608) return;
  float v;
  if (i < 49152) {                       // WqT / WkT / WvT
    int which = i >> 14, j = i & 16383;
    int n = j >> 7, k = j & 127;
    const float* W = (which == 0) ? Wq : (which == 1) ? Wk : Wv;
    v = W[((n >> 4) * 128 + k) * 16 + (n & 15)];
  } else if (i < 65536) {                // WoT
    int j = i - 49152;
    int n = j >> 7, k = j & 127;
    v = Wo[k * 128 + n];
  } else if (i < 131072) {               // W1T
    int j = i - 65536;
    int n = j >> 7, k = j & 127;
    v = W1[k * 512 + n];
  } else {                               // W2T
    int j = i - 131072;
    int n = j >> 9, k = j & 511;
    v = W2[k * 128 + n];
  }
  o[i] = f2b(v);
}

// ---------------- fused transformer block: one workgroup per batch element ----
__device__ __forceinline__ void ln128(const u16* __restrict__ src, u16* __restrict__ dst,
                                      const float* __restrict__ g,
                                      const float* __restrict__ be, int tid) {
  int row = tid >> 2, sub = tid & 3;     // 4 lanes per row
  const u16* r = src + row * LDA;
  float s = 0.f;
  #pragma unroll
  for (int j = 0; j < 32; ++j) s += b2f(r[sub + 4 * j]);
  s += __shfl_xor(s, 1); s += __shfl_xor(s, 2);
  float mu = s * 0.0078125f;
  float vv = 0.f;
  #pragma unroll
  for (int j = 0; j < 32; ++j) { float d = b2f(r[sub + 4 * j]) - mu; vv += d * d; }
  vv += __shfl_xor(vv, 1); vv += __shfl_xor(vv, 2);
  float rs = rsqrtf(vv * 0.0078125f + 1e-5f);
  u16* dr = dst + row * LDA;
  #pragma unroll
  for (int j = 0; j < 32; ++j) {
    int c = sub + 4 * j;
    dr[c] = f2b((b2f(r[c]) - mu) * rs * g[c] + be[c]);
  }
}

__global__ void __launch_bounds__(512, 1)
tblock_kernel(const float* __restrict__ xg, const u16* __restrict__ wts,
              const float* __restrict__ bo, const float* __restrict__ b1,
              const float* __restrict__ b2, const float* __restrict__ g1,
              const float* __restrict__ be1, const float* __restrict__ g2,
              const float* __restrict__ be2, float* __restrict__ out) {
  extern __shared__ u16 sm[];
  u16* xb = sm;                          // [128][LDA]  x, later x1 (bf16)
  u16* hb = sm + 128 * LDA;              // [128][LDA]  h (LN1), later h2 (LN2)
  u16* ob = sm + 2 * 128 * LDA;          // [128][LDA]  attention output (heads concat)
  u16* pb = sm + 3 * 128 * LDA;          // [128][LDA]  P (per head) / ff chunk
  u16* qs = sm + 4 * 128 * LDA;          // [128][24]   Q_h
  u16* ks = qs + 128 * 24;               // [128][24]   K_h
  u16* vs = ks + 128 * 24;               // [16][LDA]   V_h^T

  const int tid = threadIdx.x;
  const int w   = tid >> 6;              // wave 0..7, owns rows w*16..w*16+15
  const int lane = tid & 63;
  const int l15 = lane & 15;
  const int lg  = lane >> 4;             // 0..3

  const u16* WqT = wts;
  const u16* WkT = wts + 16384;
  const u16* WvT = wts + 32768;
  const u16* WoT = wts + 49152;
  const u16* W1T = wts + 65536;
  const u16* W2T = wts + 131072;

  const float* xp = xg + (size_t)blockIdx.x * 16384;
  float*       op = out + (size_t)blockIdx.x * 16384;

  // ---- S1: load x -> bf16 LDS (coalesced float4)
  for (int i = tid; i < 4096; i += 512) {
    float4 v = ((const float4*)xp)[i];
    int r = i >> 5, c = (i & 31) * 4;
    u16* d = xb + r * LDA + c;
    d[0] = f2b(v.x); d[1] = f2b(v.y); d[2] = f2b(v.z); d[3] = f2b(v.w);
  }
  __syncthreads();

  // ---- LN1: xb -> hb
  ln128(xb, hb, g1, be1, tid);
  __syncthreads();

  const f32x4 zf4 = {0.f, 0.f, 0.f, 0.f};
  const bf16x8 zb8 = zero8();

  // ---- attention, head by head
  for (int hh = 0; hh < 8; ++hh) {
    // (a) Q_h/K_h/V_h = h @ W{q,k,v}[hh]   (M=128 split across waves, N=16, K=128)
    {
      f32x4 qa = zf4, ka = zf4, va = zf4;
      #pragma unroll
      for (int kk = 0; kk < 4; ++kk) {
        bf16x8 af = *(const bf16x8*)(hb + (w * 16 + l15) * LDA + kk * 32 + lg * 8);
        bf16x8 bq = *(const bf16x8*)(WqT + (hh * 16 + l15) * 128 + kk * 32 + lg * 8);
        bf16x8 bk = *(const bf16x8*)(WkT + (hh * 16 + l15) * 128 + kk * 32 + lg * 8);
        bf16x8 bv = *(const bf16x8*)(WvT + (hh * 16 + l15) * 128 + kk * 32 + lg * 8);
        qa = mfma16(af, bq, qa);
        ka = mfma16(af, bk, ka);
        va = mfma16(af, bv, va);
      }
      #pragma unroll
      for (int rg = 0; rg < 4; ++rg) {
        int row = w * 16 + lg * 4 + rg;
        qs[row * 24 + l15] = f2b(qa[rg]);
        ks[row * 24 + l15] = f2b(ka[rg]);
        vs[l15 * LDA + row] = f2b(va[rg]);   // store V transposed: vs[e][t]
      }
    }
    __syncthreads();

    // (b) scores = Q_h K_h^T * 0.25, causal softmax -> P (bf16 in pb)
    //     K=16 zero-padded to 32; tiles nt>w are fully masked -> skipped
    {
      bf16x8 aq = (lg < 2) ? *(const bf16x8*)(qs + (w * 16 + l15) * 24 + lg * 8) : zb8;
      f32x4 sacc[8];
      #pragma unroll
      for (int nt = 0; nt < 8; ++nt) {
        if (nt <= w) {
          bf16x8 bk = (lg < 2) ? *(const bf16x8*)(ks + (nt * 16 + l15) * 24 + lg * 8) : zb8;
          sacc[nt] = mfma16(aq, bk, zf4);
        } else {
          sacc[nt] = zf4;
        }
      }
      #pragma unroll
      for (int rg = 0; rg < 4; ++rg) {
        int qrow = w * 16 + lg * 4 + rg;
        float mx = -3.0e38f;
        #pragma unroll
        for (int nt = 0; nt < 8; ++nt) if (nt <= w) {
          float sv = sacc[nt][rg] * 0.25f;
          sv = ((nt * 16 + l15) <= qrow) ? sv : -1.0e30f;
          sacc[nt][rg] = sv;
          mx = fmaxf(mx, sv);
        }
        mx = fmaxf(mx, __shfl_xor(mx, 1));
        mx = fmaxf(mx, __shfl_xor(mx, 2));
        mx = fmaxf(mx, __shfl_xor(mx, 4));
        mx = fmaxf(mx, __shfl_xor(mx, 8));
        float sum = 0.f;
        #pragma unroll
        for (int nt = 0; nt < 8; ++nt) if (nt <= w) {
          float e = __expf(sacc[nt][rg] - mx);
          sacc[nt][rg] = e;
          sum += e;
        }
        sum += __shfl_xor(sum, 1);
        sum += __shfl_xor(sum, 2);
        sum += __shfl_xor(sum, 4);
        sum += __shfl_xor(sum, 8);
        float inv = 1.f / sum;             // diagonal always present -> sum >= ~1
        #pragma unroll
        for (int nt = 0; nt < 8; ++nt) {
          pb[qrow * LDA + nt * 16 + l15] = (nt <= w) ? f2b(sacc[nt][rg] * inv) : (u16)0;
        }
      }
    }
    __syncthreads();

    // (c) O_h = P @ V_h   (M=128, N=16, K=128)
    {
      f32x4 oa = zf4;
      #pragma unroll
      for (int kk = 0; kk < 4; ++kk) {
        bf16x8 ap = *(const bf16x8*)(pb + (w * 16 + l15) * LDA + kk * 32 + lg * 8);
        bf16x8 bv = *(const bf16x8*)(vs + l15 * LDA + kk * 32 + lg * 8);
        oa = mfma16(ap, bv, oa);
      }
      #pragma unroll
      for (int rg = 0; rg < 4; ++rg) {
        int row = w * 16 + lg * 4 + rg;
        ob[row * LDA + hh * 16 + l15] = f2b(oa[rg]);
      }
    }
    __syncthreads();
  }

  // ---- S3: x1 = x + O @ Wo + bo  (overwrites xb, each wave its own rows)
  {
    f32x4 acc[8];
    #pragma unroll
    for (int nt = 0; nt < 8; ++nt) acc[nt] = zf4;
    #pragma unroll
    for (int kk = 0; kk < 4; ++kk) {
      bf16x8 ao = *(const bf16x8*)(ob + (w * 16 + l15) * LDA + kk * 32 + lg * 8);
      #pragma unroll
      for (int nt = 0; nt < 8; ++nt) {
        bf16x8 bw = *(const bf16x8*)(WoT + (nt * 16 + l15) * 128 + kk * 32 + lg * 8);
        acc[nt] = mfma16(ao, bw, acc[nt]);
      }
    }
    #pragma unroll
    for (int nt = 0; nt < 8; ++nt) {
      #pragma unroll
      for (int rg = 0; rg < 4; ++rg) {
        int row = w * 16 + lg * 4 + rg;
        int col = nt * 16 + l15;
        float v = acc[nt][rg] + bo[col] + b2f(xb[row * LDA + col]);
        xb[row * LDA + col] = f2b(v);
      }
    }
  }
  __syncthreads();

  // ---- LN2: xb(x1) -> hb(h2)
  ln128(xb, hb, g2, be2, tid);
  __syncthreads();

  // ---- FFN: out = x1 + relu(h2@W1+b1)@W2 + b2, chunked over the 512 dim
  {
    f32x4 oacc[8];
    #pragma unroll
    for (int nt = 0; nt < 8; ++nt) oacc[nt] = zf4;

    for (int cc = 0; cc < 4; ++cc) {
      f32x4 facc[8];
      #pragma unroll
      for (int nt = 0; nt < 8; ++nt) facc[nt] = zf4;
      #pragma unroll
      for (int kk = 0; kk < 4; ++kk) {
        bf16x8 ah = *(const bf16x8*)(hb + (w * 16 + l15) * LDA + kk * 32 + lg * 8);
        #pragma unroll
        for (int nt = 0; nt < 8; ++nt) {
          bf16x8 bw = *(const bf16x8*)(W1T + (cc * 128 + nt * 16 + l15) * 128 + kk * 32 + lg * 8);
          facc[nt] = mfma16(ah, bw, facc[nt]);
        }
      }
      #pragma unroll
      for (int nt = 0; nt < 8; ++nt) {
        #pragma unroll
        for (int rg = 0; rg < 4; ++rg) {
          int row = w * 16 + lg * 4 + rg;
          int col = nt * 16 + l15;
          float f = facc[nt][rg] + b1[cc * 128 + col];
          pb[row * LDA + col] = f2b(fmaxf(f, 0.f));
        }
      }
      __syncthreads();
      #pragma unroll
      for (int kk = 0; kk < 4; ++kk) {
        bf16x8 ap = *(const bf16x8*)(pb + (w * 16 + l15) * LDA + kk * 32 + lg * 8);
        #pragma unroll
        for (int nt = 0; nt < 8; ++nt) {
          bf16x8 bw = *(const bf16x8*)(W2T + (nt * 16 + l15) * 512 + cc * 128 + kk * 32 + lg * 8);
          oacc[nt] = mfma16(ap, bw, oacc[nt]);
        }
      }
      __syncthreads();
    }

    #pragma unroll
    for (int nt = 0; nt < 8; ++nt) {
      #pragma unroll
      for (int rg = 0; rg < 4; ++rg) {
        int row = w * 16 + lg * 4 + rg;
        int col = nt * 16 + l15;
        op[row * 128 + col] = oacc[nt][rg] + b2[col] + b2f(xb[row * LDA + col]);
      }
    }
  }
}

extern "C" void kernel_launch(void* const* d_in, const int* in_sizes, int n_in,
                              void* d_out, int out_size, void* d_ws, size_t ws_size,
                              hipStream_t stream) {
  const float* x   = (const float*)d_in[0];
  const float* Wq  = (const float*)d_in[1];
  const float* Wk  = (const float*)d_in[2];
  const float* Wv  = (const float*)d_in[3];
  const float* Wo  = (const float*)d_in[4];
  const float* bo  = (const float*)d_in[5];
  const float* W1  = (const float*)d_in[6];
  const float* b1  = (const float*)d_in[7];
  const float* W2  = (const float*)d_in[8];
  const float* b2  = (const float*)d_in[9];
  const float* g1  = (const float*)d_in[10];
  const float* be1 = (const float*)d_in[11];
  const float* g2  = (const float*)d_in[12];
  const float* be2 = (const float*)d_in[13];
  u16* wts = (u16*)d_ws;

  prep_kernel<<<768, 256, 0, stream>>>(Wq, Wk, Wv, Wo, W1, W2, wts);

  const int smem_bytes = (4 * 128 * LDA + 2 * 128 * 24 + 16 * LDA) * 2;  // 155904
  hipFuncSetAttribute(reinterpret_cast<const void*>(tblock_kernel),
                      hipFuncAttributeMaxDynamicSharedMemorySize, smem_bytes);
  tblock_kernel<<<1024, 512, smem_bytes, stream>>>(x, wts, bo, b1, b2, g1, be1, g2,
                                                   be2, (float*)d_out);
}

// Round 2
// 506.327 us; speedup vs baseline: 1.0309x; 1.0309x over previous
//
#include <hip/hip_runtime.h>
#include <hip/hip_bf16.h>

typedef unsigned short u16;
typedef __bf16 bf16x8 __attribute__((ext_vector_type(8)));
typedef float f32x4 __attribute__((ext_vector_type(4)));

#define LDA 136   // 128 + 8 bf16 pad: 16B-aligned rows, breaks power-of-2 bank stride

__device__ __forceinline__ u16 f2b(float f) {
  unsigned u = __builtin_bit_cast(unsigned, f);
  u = u + 0x7FFFu + ((u >> 16) & 1u);   // RNE
  return (u16)(u >> 16);
}
__device__ __forceinline__ float b2f(u16 h) {
  unsigned u = ((unsigned)h) << 16;
  return __builtin_bit_cast(float, u);
}
__device__ __forceinline__ bf16x8 zero8() {
  union { int4 i; bf16x8 v; } u;
  u.i = make_int4(0, 0, 0, 0);
  return u.v;
}
__device__ __forceinline__ f32x4 mfma16(bf16x8 a, bf16x8 b, f32x4 c) {
  return __builtin_amdgcn_mfma_f32_16x16x32_bf16(a, b, c, 0, 0, 0);
}

// ---------------- weight prep: transpose + fp32->bf16 into workspace ----------
// ws layout (u16 elements):
//   WqT [128][128] @ 0        : WqT[h*16+e][d] = Wq[h][d][e]
//   WkT [128][128] @ 16384
//   WvT [128][128] @ 32768
//   WoT [128][128] @ 49152    : WoT[n][k] = Wo[k][n]
//   W1T [512][128] @ 65536    : W1T[n][k] = W1[k][n]
//   W2T [128][512] @ 131072   : W2T[n][k] = W2[k][n]
__global__ void prep_kernel(const float* __restrict__ Wq, const float* __restrict__ Wk,
                            const float* __restrict__ Wv, const float* __restrict__ Wo,
                            const float* __restrict__ W1, const float* __restrict__ W2,
                            u16* __restrict__ o) {
  int i = blockIdx.x * 256 + threadIdx.x;
  if (i >= 196608) return;
  float v;
  if (i < 49152) {                       // WqT / WkT / WvT
    int which = i >> 14, j = i & 16383;
    int n = j >> 7, k = j & 127;
    const float* W = (which == 0) ? Wq : (which == 1) ? Wk : Wv;
    v = W[((n >> 4) * 128 + k) * 16 + (n & 15)];
  } else if (i < 65536) {                // WoT
    int j = i - 49152;
    int n = j >> 7, k = j & 127;
    v = Wo[k * 128 + n];
  } else if (i < 131072) {               // W1T
    int j = i - 65536;
    int n = j >> 7, k = j & 127;
    v = W1[k * 512 + n];
  } else {                               // W2T
    int j = i - 131072;
    int n = j >> 9, k = j & 511;
    v = W2[k * 128 + n];
  }
  o[i] = f2b(v);
}

// LayerNorm from registers held in MFMA C-layout: lane holds v[nt][rg] =
// x[r0+rg][nt*16+l15]. Row = (lg,rg); the 128 cols of a row live in the 16
// lanes sharing lg (l15=0..15) x 8 regs -> shfl_xor(1,2,4,8) row-reduce.
__device__ __forceinline__ void ln_regs(const float (&v)[8][4], const float* __restrict__ g,
                                        const float* __restrict__ be,
                                        u16* __restrict__ dst, int r0, int l15) {
  #pragma unroll
  for (int rg = 0; rg < 4; ++rg) {
    float s = 0.f;
    #pragma unroll
    for (int nt = 0; nt < 8; ++nt) s += v[nt][rg];
    s += __shfl_xor(s, 1); s += __shfl_xor(s, 2);
    s += __shfl_xor(s, 4); s += __shfl_xor(s, 8);
    float mu = s * 0.0078125f;
    float vv = 0.f;
    #pragma unroll
    for (int nt = 0; nt < 8; ++nt) { float d = v[nt][rg] - mu; vv += d * d; }
    vv += __shfl_xor(vv, 1); vv += __shfl_xor(vv, 2);
    vv += __shfl_xor(vv, 4); vv += __shfl_xor(vv, 8);
    float rs = rsqrtf(vv * 0.0078125f + 1e-5f);
    #pragma unroll
    for (int nt = 0; nt < 8; ++nt) {
      int col = nt * 16 + l15;
      dst[(r0 + rg) * LDA + col] = f2b((v[nt][rg] - mu) * rs * g[col] + be[col]);
    }
  }
}

// ---------------- fused transformer block: one workgroup per batch element ----
// 8 waves. Wave w owns row-stripe [w*16, w*16+16) for GEMM phases and head w
// for attention. 3 barriers total.
__global__ void __launch_bounds__(512, 2)
tblock_kernel(const float* __restrict__ xg, const u16* __restrict__ wts,
              const float* __restrict__ bo, const float* __restrict__ b1,
              const float* __restrict__ b2, const float* __restrict__ g1,
              const float* __restrict__ be1, const float* __restrict__ g2,
              const float* __restrict__ be2, float* __restrict__ out) {
  extern __shared__ u16 sm[];
  u16* hb = sm;                          // [128][LDA] h (LN1) -> V^T[e_g][t] -> h2 (LN2)
  u16* qs = sm + 128 * LDA;              // [128][LDA] Q[t][h*16+e] -> O[t][h*16+e] (in-place)
  u16* ks = sm + 2 * 128 * LDA;          // [128][LDA] K[s][h*16+e]
  u16* pb = sm + 3 * 128 * LDA;          // [128][LDA] wave-private P slices / FFN slices

  const int tid = threadIdx.x;
  const int w   = tid >> 6;
  const int lane = tid & 63;
  const int l15 = lane & 15;
  const int lg  = lane >> 4;             // 0..3
  const int r0  = w * 16 + lg * 4;       // lane covers rows r0..r0+3 in C-layout

  const u16* WqT = wts;
  const u16* WkT = wts + 16384;
  const u16* WvT = wts + 32768;
  const u16* WoT = wts + 49152;
  const u16* W1T = wts + 65536;
  const u16* W2T = wts + 131072;

  const float* xp = xg + (size_t)blockIdx.x * 16384;
  float*       op = out + (size_t)blockIdx.x * 16384;

  const f32x4 zf4 = {0.f, 0.f, 0.f, 0.f};
  const bf16x8 zb8 = zero8();

  // ---- S1: load residual x into registers (C-layout), fp32
  float xr[8][4];
  #pragma unroll
  for (int nt = 0; nt < 8; ++nt)
    #pragma unroll
    for (int rg = 0; rg < 4; ++rg)
      xr[nt][rg] = xp[(r0 + rg) * 128 + nt * 16 + l15];

  // ---- LN1 (wave-private): xr -> hb rows [w*16, w*16+16)
  ln_regs(xr, g1, be1, hb, r0, l15);
  // no barrier: QKV below reads only this wave's own hb rows

  // ---- QKV GEMM: rows w*16..+15 x (Wq|Wk|Wv), N=384, K=128
  bf16x8 af[4];
  #pragma unroll
  for (int kk = 0; kk < 4; ++kk)
    af[kk] = *(const bf16x8*)(hb + (w * 16 + l15) * LDA + kk * 32 + lg * 8);

  {
    f32x4 qa[8];
    #pragma unroll
    for (int nt = 0; nt < 8; ++nt) qa[nt] = zf4;
    #pragma unroll
    for (int kk = 0; kk < 4; ++kk)
      #pragma unroll
      for (int nt = 0; nt < 8; ++nt)
        qa[nt] = mfma16(af[kk], *(const bf16x8*)(WqT + (nt * 16 + l15) * 128 + kk * 32 + lg * 8), qa[nt]);
    #pragma unroll
    for (int nt = 0; nt < 8; ++nt)
      #pragma unroll
      for (int rg = 0; rg < 4; ++rg)
        qs[(r0 + rg) * LDA + nt * 16 + l15] = f2b(qa[nt][rg]);
  }
  {
    f32x4 ka[8];
    #pragma unroll
    for (int nt = 0; nt < 8; ++nt) ka[nt] = zf4;
    #pragma unroll
    for (int kk = 0; kk < 4; ++kk)
      #pragma unroll
      for (int nt = 0; nt < 8; ++nt)
        ka[nt] = mfma16(af[kk], *(const bf16x8*)(WkT + (nt * 16 + l15) * 128 + kk * 32 + lg * 8), ka[nt]);
    #pragma unroll
    for (int nt = 0; nt < 8; ++nt)
      #pragma unroll
      for (int rg = 0; rg < 4; ++rg)
        ks[(r0 + rg) * LDA + nt * 16 + l15] = f2b(ka[nt][rg]);
  }
  f32x4 va[8];
  {
    #pragma unroll
    for (int nt = 0; nt < 8; ++nt) va[nt] = zf4;
    #pragma unroll
    for (int kk = 0; kk < 4; ++kk)
      #pragma unroll
      for (int nt = 0; nt < 8; ++nt)
        va[nt] = mfma16(af[kk], *(const bf16x8*)(WvT + (nt * 16 + l15) * 128 + kk * 32 + lg * 8), va[nt]);
  }

  __syncthreads();   // [bar 1] all waves done reading hb; qs/ks written

  // ---- write V^T over hb: V^T[e_global][t]  (V rows w*16..+15 from regs)
  #pragma unroll
  for (int nt = 0; nt < 8; ++nt)
    #pragma unroll
    for (int rg = 0; rg < 4; ++rg)
      hb[(nt * 16 + l15) * LDA + r0 + rg] = f2b(va[nt][rg]);

  __syncthreads();   // [bar 2] V^T / qs / ks visible to all

  // ---- attention: wave w == head w. m-tile loop over 8 query blocks.
  // P bounces through wave-private pb rows; O written in-place into the
  // just-consumed qs stripe (cols w*16..+15).
  for (int mt = 0; mt < 8; ++mt) {
    bf16x8 aq = zb8;
    if (lg < 2) aq = *(const bf16x8*)(qs + (mt * 16 + l15) * LDA + w * 16 + lg * 8);

    f32x4 sacc[8];
    #pragma unroll
    for (int nt = 0; nt < 8; ++nt) {
      if (nt <= mt) {
        bf16x8 bk = zb8;
        if (lg < 2) bk = *(const bf16x8*)(ks + (nt * 16 + l15) * LDA + w * 16 + lg * 8);
        sacc[nt] = mfma16(aq, bk, zf4);
      } else {
        sacc[nt] = zf4;
      }
    }
    // softmax per row (row = lg*4+rg local; cols across l15 lanes x nt regs)
    #pragma unroll
    for (int rg = 0; rg < 4; ++rg) {
      float mx = -3.0e38f;
      #pragma unroll
      for (int nt = 0; nt < 8; ++nt) if (nt <= mt) {
        float sv = sacc[nt][rg] * 0.25f;
        if (nt == mt) sv = (l15 <= lg * 4 + rg) ? sv : -1.0e30f;  // diag causal mask
        sacc[nt][rg] = sv;
        mx = fmaxf(mx, sv);
      }
      mx = fmaxf(mx, __shfl_xor(mx, 1));
      mx = fmaxf(mx, __shfl_xor(mx, 2));
      mx = fmaxf(mx, __shfl_xor(mx, 4));
      mx = fmaxf(mx, __shfl_xor(mx, 8));
      float sum = 0.f;
      #pragma unroll
      for (int nt = 0; nt < 8; ++nt) if (nt <= mt) {
        float e = __expf(sacc[nt][rg] - mx);
        sacc[nt][rg] = e;
        sum += e;
      }
      sum += __shfl_xor(sum, 1);
      sum += __shfl_xor(sum, 2);
      sum += __shfl_xor(sum, 4);
      sum += __shfl_xor(sum, 8);
      float inv = 1.f / sum;
      #pragma unroll
      for (int nt = 0; nt < 8; ++nt) {
        float pv = (nt <= mt) ? sacc[nt][rg] * inv : 0.f;   // zero-fill for even K-chunks
        pb[(w * 16 + lg * 4 + rg) * LDA + nt * 16 + l15] = f2b(pv);
      }
    }
    // PV: O_block(16x16) = P(16 x (mt+1)*16) @ V_h
    f32x4 oa = zf4;
    const int nch = (mt + 2) >> 1;
    for (int kk = 0; kk < nch; ++kk) {
      bf16x8 ap = *(const bf16x8*)(pb + (w * 16 + l15) * LDA + kk * 32 + lg * 8);
      bf16x8 bv = *(const bf16x8*)(hb + (w * 16 + l15) * LDA + kk * 32 + lg * 8);
      oa = mfma16(ap, bv, oa);
    }
    // in-place O bounce into qs (rows mt*16.., cols w*16.. — this wave's
    // aq read of the same region happened above; WAR within-wave is ordered)
    #pragma unroll
    for (int rg = 0; rg < 4; ++rg)
      qs[(mt * 16 + lg * 4 + rg) * LDA + w * 16 + l15] = f2b(oa[rg]);
  }

  __syncthreads();   // [bar 3] all O blocks in qs; pb free; V^T (hb) dead

  // ---- Wo GEMM + residual: x1 = x + O @ Wo + bo   (rows w*16..+15)
  {
    f32x4 acc[8];
    #pragma unroll
    for (int nt = 0; nt < 8; ++nt) acc[nt] = zf4;
    #pragma unroll
    for (int kk = 0; kk < 4; ++kk) {
      bf16x8 ao = *(const bf16x8*)(qs + (w * 16 + l15) * LDA + kk * 32 + lg * 8);
      #pragma unroll
      for (int nt = 0; nt < 8; ++nt)
        acc[nt] = mfma16(ao, *(const bf16x8*)(WoT + (nt * 16 + l15) * 128 + kk * 32 + lg * 8), acc[nt]);
    }
    #pragma unroll
    for (int nt = 0; nt < 8; ++nt)
      #pragma unroll
      for (int rg = 0; rg < 4; ++rg)
        xr[nt][rg] += acc[nt][rg] + bo[nt * 16 + l15];
  }

  // ---- LN2 (wave-private): x1 regs -> h2 into hb rows w*16..+15
  ln_regs(xr, g2, be2, hb, r0, l15);
  // no barrier: FFN reads only own hb/pb rows from here on

  // ---- FFN: out = x1 + relu(h2@W1+b1)@W2 + b2, 4 chunks of 128, wave-private
  {
    f32x4 oacc[8];
    #pragma unroll
    for (int nt = 0; nt < 8; ++nt) oacc[nt] = zf4;

    bf16x8 ah[4];
    #pragma unroll
    for (int kk = 0; kk < 4; ++kk)
      ah[kk] = *(const bf16x8*)(hb + (w * 16 + l15) * LDA + kk * 32 + lg * 8);

    for (int cc = 0; cc < 4; ++cc) {
      f32x4 facc[8];
      #pragma unroll
      for (int nt = 0; nt < 8; ++nt) facc[nt] = zf4;
      #pragma unroll
      for (int kk = 0; kk < 4; ++kk)
        #pragma unroll
        for (int nt = 0; nt < 8; ++nt)
          facc[nt] = mfma16(ah[kk],
              *(const bf16x8*)(W1T + (cc * 128 + nt * 16 + l15) * 128 + kk * 32 + lg * 8), facc[nt]);
      #pragma unroll
      for (int nt = 0; nt < 8; ++nt)
        #pragma unroll
        for (int rg = 0; rg < 4; ++rg) {
          float f = facc[nt][rg] + b1[cc * 128 + nt * 16 + l15];
          pb[(r0 + rg) * LDA + nt * 16 + l15] = f2b(fmaxf(f, 0.f));
        }
      #pragma unroll
      for (int kk = 0; kk < 4; ++kk) {
        bf16x8 ap = *(const bf16x8*)(pb + (w * 16 + l15) * LDA + kk * 32 + lg * 8);
        #pragma unroll
        for (int nt = 0; nt < 8; ++nt)
          oacc[nt] = mfma16(ap,
              *(const bf16x8*)(W2T + (nt * 16 + l15) * 512 + cc * 128 + kk * 32 + lg * 8), oacc[nt]);
      }
    }

    #pragma unroll
    for (int nt = 0; nt < 8; ++nt)
      #pragma unroll
      for (int rg = 0; rg < 4; ++rg)
        op[(r0 + rg) * 128 + nt * 16 + l15] = oacc[nt][rg] + b2[nt * 16 + l15] + xr[nt][rg];
  }
}

extern "C" void kernel_launch(void* const* d_in, const int* in_sizes, int n_in,
                              void* d_out, int out_size, void* d_ws, size_t ws_size,
                              hipStream_t stream) {
  const float* x   = (const float*)d_in[0];
  const float* Wq  = (const float*)d_in[1];
  const float* Wk  = (const float*)d_in[2];
  const float* Wv  = (const float*)d_in[3];
  const float* Wo  = (const float*)d_in[4];
  const float* bo  = (const float*)d_in[5];
  const float* W1  = (const float*)d_in[6];
  const float* b1  = (const float*)d_in[7];
  const float* W2  = (const float*)d_in[8];
  const float* b2  = (const float*)d_in[9];
  const float* g1  = (const float*)d_in[10];
  const float* be1 = (const float*)d_in[11];
  const float* g2  = (const float*)d_in[12];
  const float* be2 = (const float*)d_in[13];
  u16* wts = (u16*)d_ws;

  prep_kernel<<<768, 256, 0, stream>>>(Wq, Wk, Wv, Wo, W1, W2, wts);

  const int smem_bytes = 4 * 128 * LDA * 2;  // 139264
  hipFuncSetAttribute(reinterpret_cast<const void*>(tblock_kernel),
                      hipFuncAttributeMaxDynamicSharedMemorySize, smem_bytes);
  tblock_kernel<<<1024, 512, smem_bytes, stream>>>(x, wts, bo, b1, b2, g1, be1, g2,
                                                   be2, (float*)d_out);
}

// Round 3
// 386.293 us; speedup vs baseline: 1.3512x; 1.3107x over previous
//
#include <hip/hip_runtime.h>
#include <hip/hip_bf16.h>

typedef unsigned short u16;
typedef unsigned int u32;
typedef __bf16 bf16x8 __attribute__((ext_vector_type(8)));
typedef float f32x4 __attribute__((ext_vector_type(4)));

#define LDA 136   // 128 + 8 bf16 pad: 16B-aligned rows, non-pow2 bank stride

__device__ __forceinline__ u16 f2b(float f) {
  __bf16 b = (__bf16)f;                  // native cvt (RNE), 1 op
  return __builtin_bit_cast(u16, b);
}
__device__ __forceinline__ float b2f(u16 h) {
  u32 u = ((u32)h) << 16;
  return __builtin_bit_cast(float, u);
}
__device__ __forceinline__ u32 pk2(float lo, float hi) {
  return (u32)f2b(lo) | ((u32)f2b(hi) << 16);
}
__device__ __forceinline__ bf16x8 zero8() {
  union { int4 i; bf16x8 v; } u;
  u.i = make_int4(0, 0, 0, 0);
  return u.v;
}
__device__ __forceinline__ f32x4 mfma16(bf16x8 a, bf16x8 b, f32x4 c) {
  return __builtin_amdgcn_mfma_f32_16x16x32_bf16(a, b, c, 0, 0, 0);
}

// ---------------- weight prep: transpose + fp32->bf16 into workspace ----------
// ws layout (u16): WqT[128][128]@0, WkT@16384, WvT@32768, WoT@49152,
//                  W1T[512][128]@65536, W2T[128][512]@131072
__global__ void prep_kernel(const float* __restrict__ Wq, const float* __restrict__ Wk,
                            const float* __restrict__ Wv, const float* __restrict__ Wo,
                            const float* __restrict__ W1, const float* __restrict__ W2,
                            u16* __restrict__ o) {
  int i = blockIdx.x * 256 + threadIdx.x;
  if (i >= 196608) return;
  float v;
  if (i < 49152) {
    int which = i >> 14, j = i & 16383;
    int n = j >> 7, k = j & 127;
    const float* W = (which == 0) ? Wq : (which == 1) ? Wk : Wv;
    v = W[((n >> 4) * 128 + k) * 16 + (n & 15)];
  } else if (i < 65536) {
    int j = i - 49152;
    v = Wo[(j & 127) * 128 + (j >> 7)];
  } else if (i < 131072) {
    int j = i - 65536;
    v = W1[(j & 127) * 512 + (j >> 7)];
  } else {
    int j = i - 131072;
    v = W2[(j & 511) * 128 + (j >> 9)];
  }
  o[i] = f2b(v);
}

// LayerNorm from regs in MFMA C-layout: v[nt][rg] = x[r0+rg][nt*16+l15].
__device__ __forceinline__ void ln_regs(const float (&v)[8][4], const float* __restrict__ g,
                                        const float* __restrict__ be,
                                        u16* __restrict__ dst, int r0, int l15) {
  #pragma unroll
  for (int rg = 0; rg < 4; ++rg) {
    float s = 0.f;
    #pragma unroll
    for (int nt = 0; nt < 8; ++nt) s += v[nt][rg];
    s += __shfl_xor(s, 1); s += __shfl_xor(s, 2);
    s += __shfl_xor(s, 4); s += __shfl_xor(s, 8);
    float mu = s * 0.0078125f;
    float vv = 0.f;
    #pragma unroll
    for (int nt = 0; nt < 8; ++nt) { float d = v[nt][rg] - mu; vv += d * d; }
    vv += __shfl_xor(vv, 1); vv += __shfl_xor(vv, 2);
    vv += __shfl_xor(vv, 4); vv += __shfl_xor(vv, 8);
    float rs = rsqrtf(vv * 0.0078125f + 1e-5f);
    #pragma unroll
    for (int nt = 0; nt < 8; ++nt) {
      int col = nt * 16 + l15;
      dst[(r0 + rg) * LDA + col] = f2b((v[nt][rg] - mu) * rs * g[col] + be[col]);
    }
  }
}

// ---------------- fused transformer block, 78KB LDS -> 2 blocks/CU ------------
__global__ void __launch_bounds__(512, 4)
tblock_kernel(const float* __restrict__ xg, const u16* __restrict__ wts,
              const float* __restrict__ bo, const float* __restrict__ b1,
              const float* __restrict__ b2, const float* __restrict__ g1,
              const float* __restrict__ be1, const float* __restrict__ g2,
              const float* __restrict__ be2, float* __restrict__ out) {
  extern __shared__ u16 sm[];
  u16* hb = sm;                  // [128][LDA] h -> K (C-layout) -> V^T -> h2
  u16* qs = sm + 128 * LDA;      // [128][LDA] Q -> O (in-place) -> x1 (bf16)
  u16* pb = sm + 2 * 128 * LDA;  // [8 waves][16][40] FFN relu chunk

  const int tid = threadIdx.x;
  const int w    = tid >> 6;
  const int lane = tid & 63;
  const int l15  = lane & 15;
  const int lg   = lane >> 4;
  const int r0   = w * 16 + lg * 4;

  const u16* WqT = wts;
  const u16* WkT = wts + 16384;
  const u16* WvT = wts + 32768;
  const u16* WoT = wts + 49152;
  const u16* W1T = wts + 65536;
  const u16* W2T = wts + 131072;

  const float* xp = xg + (size_t)blockIdx.x * 16384;
  float*       op = out + (size_t)blockIdx.x * 16384;

  const f32x4 zf4 = {0.f, 0.f, 0.f, 0.f};
  const bf16x8 zb8 = zero8();

  // ---- LN1: load x (transient regs) -> h into own hb stripe
  {
    float xr[8][4];
    #pragma unroll
    for (int nt = 0; nt < 8; ++nt)
      #pragma unroll
      for (int rg = 0; rg < 4; ++rg)
        xr[nt][rg] = xp[(r0 + rg) * 128 + nt * 16 + l15];
    ln_regs(xr, g1, be1, hb, r0, l15);
  }

  // ---- QKV GEMMs (rows w*16..+15): Q -> qs, K -> hb (over dead h), V -> regs
  bf16x8 af[4];
  #pragma unroll
  for (int kk = 0; kk < 4; ++kk)
    af[kk] = *(const bf16x8*)(hb + (w * 16 + l15) * LDA + kk * 32 + lg * 8);

  {
    f32x4 qa[8];
    #pragma unroll
    for (int nt = 0; nt < 8; ++nt) qa[nt] = zf4;
    #pragma unroll
    for (int kk = 0; kk < 4; ++kk)
      #pragma unroll
      for (int nt = 0; nt < 8; ++nt)
        qa[nt] = mfma16(af[kk], *(const bf16x8*)(WqT + (nt * 16 + l15) * 128 + kk * 32 + lg * 8), qa[nt]);
    #pragma unroll
    for (int nt = 0; nt < 8; ++nt)
      #pragma unroll
      for (int rg = 0; rg < 4; ++rg)
        qs[(r0 + rg) * LDA + nt * 16 + l15] = f2b(qa[nt][rg]);
  }
  {
    f32x4 ka[8];
    #pragma unroll
    for (int nt = 0; nt < 8; ++nt) ka[nt] = zf4;
    #pragma unroll
    for (int kk = 0; kk < 4; ++kk)
      #pragma unroll
      for (int nt = 0; nt < 8; ++nt)
        ka[nt] = mfma16(af[kk], *(const bf16x8*)(WkT + (nt * 16 + l15) * 128 + kk * 32 + lg * 8), ka[nt]);
    #pragma unroll
    for (int nt = 0; nt < 8; ++nt)
      #pragma unroll
      for (int rg = 0; rg < 4; ++rg)
        hb[(r0 + rg) * LDA + nt * 16 + l15] = f2b(ka[nt][rg]);   // K over dead h
  }
  f32x4 va[8];
  {
    #pragma unroll
    for (int nt = 0; nt < 8; ++nt) va[nt] = zf4;
    #pragma unroll
    for (int kk = 0; kk < 4; ++kk)
      #pragma unroll
      for (int nt = 0; nt < 8; ++nt)
        va[nt] = mfma16(af[kk], *(const bf16x8*)(WvT + (nt * 16 + l15) * 128 + kk * 32 + lg * 8), va[nt]);
  }

  __syncthreads();   // [bar1] K,Q complete

  // ---- K fragments of head w into regs (frees hb for V^T)
  bf16x8 bk[8];
  #pragma unroll
  for (int st = 0; st < 8; ++st) {
    bk[st] = zb8;
    if (lg < 2) bk[st] = *(const bf16x8*)(hb + (st * 16 + l15) * LDA + w * 16 + lg * 8);
  }

  __syncthreads();   // [bar2] all K reads done

  // ---- V^T over hb: V^T[e][t], packed b64 (4 consecutive t per lane)
  #pragma unroll
  for (int nt = 0; nt < 8; ++nt) {
    union { u16 h[4]; ushort4 s4; } vw;
    #pragma unroll
    for (int rg = 0; rg < 4; ++rg) vw.h[rg] = f2b(va[nt][rg]);
    *(ushort4*)(hb + (nt * 16 + l15) * LDA + w * 16 + lg * 4) = vw.s4;
  }

  __syncthreads();   // [bar3] V^T ready

  // ---- attention: wave w = head w. S^T = mfma(K,Q): lane owns row t = mt*16+l15.
  #pragma unroll 1
  for (int mt = 0; mt < 8; ++mt) {
    bf16x8 aq = zb8;
    if (lg < 2) aq = *(const bf16x8*)(qs + (mt * 16 + l15) * LDA + w * 16 + lg * 8);

    f32x4 sacc[8];
    #pragma unroll
    for (int st = 0; st < 8; ++st)
      sacc[st] = (st <= mt) ? mfma16(bk[st], aq, zf4) : zf4;

    // scale + causal mask + row max (in-lane over st,rg; cross-lg via 2 shfl)
    float mx = -3.0e38f;
    #pragma unroll
    for (int st = 0; st < 8; ++st) if (st <= mt) {
      #pragma unroll
      for (int rg = 0; rg < 4; ++rg) {
        float sv = sacc[st][rg] * 0.25f;
        bool ok = (st < mt) || ((lg * 4 + rg) <= l15);
        sv = ok ? sv : -1.0e30f;
        sacc[st][rg] = sv;
        mx = fmaxf(mx, sv);
      }
    }
    mx = fmaxf(mx, __shfl_xor(mx, 16));
    mx = fmaxf(mx, __shfl_xor(mx, 32));
    float sum = 0.f;
    #pragma unroll
    for (int st = 0; st < 8; ++st) if (st <= mt) {
      #pragma unroll
      for (int rg = 0; rg < 4; ++rg) {
        float e = __expf(sacc[st][rg] - mx);
        sacc[st][rg] = e;
        sum += e;
      }
    }
    sum += __shfl_xor(sum, 16);
    sum += __shfl_xor(sum, 32);
    float inv = 1.f / sum;

    // PV: P^T B-fragments gathered in-register (8 shfl per 32-s chunk)
    f32x4 oacc = zf4;
    #pragma unroll
    for (int kk = 0; kk < 4; ++kk) if (kk <= (mt >> 1)) {
      u32 A0 = pk2(sacc[2 * kk][0] * inv, sacc[2 * kk][1] * inv);
      u32 A1 = pk2(sacc[2 * kk][2] * inv, sacc[2 * kk][3] * inv);
      u32 B0 = 0, B1 = 0;
      if (2 * kk + 1 <= mt) {
        B0 = pk2(sacc[2 * kk + 1][0] * inv, sacc[2 * kk + 1][1] * inv);
        B1 = pk2(sacc[2 * kk + 1][2] * inv, sacc[2 * kk + 1][3] * inv);
      }
      int src0 = ((lg & 1) * 2) * 16 + l15;
      u32 a0 = __shfl(A0, src0),      a1 = __shfl(A1, src0);
      u32 a2 = __shfl(A0, src0 + 16), a3 = __shfl(A1, src0 + 16);
      u32 c0 = __shfl(B0, src0),      c1 = __shfl(B1, src0);
      u32 c2 = __shfl(B0, src0 + 16), c3 = __shfl(B1, src0 + 16);
      union { u32 u[4]; bf16x8 v; } fr;
      bool lo = (lg < 2);
      fr.u[0] = lo ? a0 : c0; fr.u[1] = lo ? a1 : c1;
      fr.u[2] = lo ? a2 : c2; fr.u[3] = lo ? a3 : c3;
      bf16x8 av = *(const bf16x8*)(hb + (w * 16 + l15) * LDA + kk * 32 + lg * 8);
      oacc = mfma16(av, fr.v, oacc);   // O^T[e][t]: lane = (e=lg*4+rg, t=l15)
    }
    union { u16 h[4]; ushort4 s4; } ow;
    #pragma unroll
    for (int rg = 0; rg < 4; ++rg) ow.h[rg] = f2b(oacc[rg]);
    *(ushort4*)(qs + (mt * 16 + l15) * LDA + w * 16 + lg * 4) = ow.s4;
  }

  __syncthreads();   // [bar4] all O written

  // ---- Wo GEMM + residual (x re-loaded; prefetched ahead of MFMAs)
  float x1[8][4];
  {
    float xrl[8][4];
    #pragma unroll
    for (int nt = 0; nt < 8; ++nt)
      #pragma unroll
      for (int rg = 0; rg < 4; ++rg)
        xrl[nt][rg] = xp[(r0 + rg) * 128 + nt * 16 + l15];

    f32x4 acc[8];
    #pragma unroll
    for (int nt = 0; nt < 8; ++nt) acc[nt] = zf4;
    #pragma unroll
    for (int kk = 0; kk < 4; ++kk) {
      bf16x8 ao = *(const bf16x8*)(qs + (w * 16 + l15) * LDA + kk * 32 + lg * 8);
      #pragma unroll
      for (int nt = 0; nt < 8; ++nt)
        acc[nt] = mfma16(ao, *(const bf16x8*)(WoT + (nt * 16 + l15) * 128 + kk * 32 + lg * 8), acc[nt]);
    }
    #pragma unroll
    for (int nt = 0; nt < 8; ++nt)
      #pragma unroll
      for (int rg = 0; rg < 4; ++rg)
        x1[nt][rg] = acc[nt][rg] + bo[nt * 16 + l15] + xrl[nt][rg];
  }
  // park x1 (bf16) in qs own stripe; h2 -> hb own stripe
  #pragma unroll
  for (int nt = 0; nt < 8; ++nt)
    #pragma unroll
    for (int rg = 0; rg < 4; ++rg)
      qs[(r0 + rg) * LDA + nt * 16 + l15] = f2b(x1[nt][rg]);
  ln_regs(x1, g2, be2, hb, r0, l15);

  // ---- FFN (wave-private, chunked relu bounce through pb)
  {
    bf16x8 ah[4];
    #pragma unroll
    for (int kk = 0; kk < 4; ++kk)
      ah[kk] = *(const bf16x8*)(hb + (w * 16 + l15) * LDA + kk * 32 + lg * 8);

    f32x4 oacc[8];
    #pragma unroll
    for (int nt = 0; nt < 8; ++nt) oacc[nt] = zf4;
    u16* pw = pb + w * 640;   // [16][40]

    #pragma unroll 1
    for (int cc = 0; cc < 4; ++cc) {
      f32x4 facc[8];
      #pragma unroll
      for (int nt = 0; nt < 8; ++nt) facc[nt] = zf4;
      #pragma unroll
      for (int kk = 0; kk < 4; ++kk)
        #pragma unroll
        for (int nt = 0; nt < 8; ++nt)
          facc[nt] = mfma16(ah[kk],
              *(const bf16x8*)(W1T + (cc * 128 + nt * 16 + l15) * 128 + kk * 32 + lg * 8), facc[nt]);

      #pragma unroll
      for (int kk = 0; kk < 4; ++kk) {
        #pragma unroll
        for (int hh = 0; hh < 2; ++hh) {
          int nt2 = 2 * kk + hh;
          #pragma unroll
          for (int rg = 0; rg < 4; ++rg) {
            float f = facc[nt2][rg] + b1[cc * 128 + nt2 * 16 + l15];
            pw[(lg * 4 + rg) * 40 + hh * 16 + l15] = f2b(fmaxf(f, 0.f));
          }
        }
        bf16x8 ap = *(const bf16x8*)(pw + l15 * 40 + lg * 8);
        #pragma unroll
        for (int nt = 0; nt < 8; ++nt)
          oacc[nt] = mfma16(ap,
              *(const bf16x8*)(W2T + (nt * 16 + l15) * 512 + cc * 128 + kk * 32 + lg * 8), oacc[nt]);
      }
    }

    #pragma unroll
    for (int nt = 0; nt < 8; ++nt)
      #pragma unroll
      for (int rg = 0; rg < 4; ++rg)
        op[(r0 + rg) * 128 + nt * 16 + l15] =
            oacc[nt][rg] + b2[nt * 16 + l15] + b2f(qs[(r0 + rg) * LDA + nt * 16 + l15]);
  }
}

extern "C" void kernel_launch(void* const* d_in, const int* in_sizes, int n_in,
                              void* d_out, int out_size, void* d_ws, size_t ws_size,
                              hipStream_t stream) {
  const float* x   = (const float*)d_in[0];
  const float* Wq  = (const float*)d_in[1];
  const float* Wk  = (const float*)d_in[2];
  const float* Wv  = (const float*)d_in[3];
  const float* Wo  = (const float*)d_in[4];
  const float* bo  = (const float*)d_in[5];
  const float* W1  = (const float*)d_in[6];
  const float* b1  = (const float*)d_in[7];
  const float* W2  = (const float*)d_in[8];
  const float* b2  = (const float*)d_in[9];
  const float* g1  = (const float*)d_in[10];
  const float* be1 = (const float*)d_in[11];
  const float* g2  = (const float*)d_in[12];
  const float* be2 = (const float*)d_in[13];
  u16* wts = (u16*)d_ws;

  prep_kernel<<<768, 256, 0, stream>>>(Wq, Wk, Wv, Wo, W1, W2, wts);

  const int smem_bytes = (2 * 128 * LDA + 8 * 640) * 2;  // 79872 -> 2 blocks/CU
  hipFuncSetAttribute(reinterpret_cast<const void*>(tblock_kernel),
                      hipFuncAttributeMaxDynamicSharedMemorySize, smem_bytes);
  tblock_kernel<<<1024, 512, smem_bytes, stream>>>(x, wts, bo, b1, b2, g1, be1, g2,
                                                   be2, (float*)d_out);
}

// Round 4
// 144.631 us; speedup vs baseline: 3.6089x; 2.6709x over previous
//
#include <hip/hip_runtime.h>
#include <hip/hip_bf16.h>

typedef unsigned short u16;
typedef unsigned int u32;
typedef __bf16 bf16x8 __attribute__((ext_vector_type(8)));
typedef float f32x4 __attribute__((ext_vector_type(4)));

#define LDA 136   // 128 + 8 bf16 pad: 16B-aligned rows, non-pow2 bank stride

__device__ __forceinline__ u16 f2b(float f) {
  __bf16 b = (__bf16)f;
  return __builtin_bit_cast(u16, b);
}
__device__ __forceinline__ float b2f(u16 h) {
  u32 u = ((u32)h) << 16;
  return __builtin_bit_cast(float, u);
}
__device__ __forceinline__ u32 pk2(float lo, float hi) {
  return (u32)f2b(lo) | ((u32)f2b(hi) << 16);
}
__device__ __forceinline__ bf16x8 zero8() {
  union { int4 i; bf16x8 v; } u;
  u.i = make_int4(0, 0, 0, 0);
  return u.v;
}
__device__ __forceinline__ f32x4 mfma16(bf16x8 a, bf16x8 b, f32x4 c) {
  return __builtin_amdgcn_mfma_f32_16x16x32_bf16(a, b, c, 0, 0, 0);
}

// Build a 16x16x32 B- (or A-) fragment whose k-dim runs over t=0..31 from the
// C-layout fragment pair {ve=frag[2kk], vo=frag[2kk+1]} held wave-wide:
// source lane (l15',lg') reg[rg] = M[t=tile*16+lg'*4+rg][l15'].
// Target lane (l15,lg) wants M[t=kk*32+lg*8+j][l15], j=0..7.
//   tile = 2kk + (lg>>1); lg' = (lg&1)*2 + (j>>2); rg = j&3.
// Verified pattern (R3 P^T gather, passed absmax).
__device__ __forceinline__ bf16x8 gatherB(const f32x4& ve, const f32x4& vo,
                                          bool odd_valid, float scale,
                                          int l15, int lg) {
  u32 pe0 = pk2(ve[0] * scale, ve[1] * scale);
  u32 pe1 = pk2(ve[2] * scale, ve[3] * scale);
  u32 po0 = 0, po1 = 0;
  if (odd_valid) {
    po0 = pk2(vo[0] * scale, vo[1] * scale);
    po1 = pk2(vo[2] * scale, vo[3] * scale);
  }
  int s0 = ((lg & 1) * 2) * 16 + l15;
  u32 a0 = __shfl(pe0, s0),      a1 = __shfl(pe1, s0);
  u32 a2 = __shfl(pe0, s0 + 16), a3 = __shfl(pe1, s0 + 16);
  u32 b0 = __shfl(po0, s0),      b1 = __shfl(po1, s0);
  u32 b2 = __shfl(po0, s0 + 16), b3 = __shfl(po1, s0 + 16);
  union { u32 u[4]; bf16x8 v; } fr;
  bool lo = (lg < 2);                 // selects tile = 2kk vs 2kk+1
  fr.u[0] = lo ? a0 : b0; fr.u[1] = lo ? a1 : b1;
  fr.u[2] = lo ? a2 : b2; fr.u[3] = lo ? a3 : b3;
  return fr.v;
}

// ---------------- weight prep: transpose + fp32->bf16 into workspace ----------
// ws (u16): WqT[128][128]@0  (WqT[h*16+e][d]=Wq[h][d][e]), WkT@16384, WvT@32768,
//           WoT@49152 (WoT[n][k]=Wo[k][n]),
//           W1T[512][128]@65536 (W1T[n][k]=W1[k][n]),
//           W2S@131072: [cc][nt][16][128]: W2S[((cc*8+nt)*16+r)*128+c]
//                        = W2[(cc*128+c)*128 + nt*16+r]   (k=cc*128+c, n=nt*16+r)
__global__ void prep_kernel(const float* __restrict__ Wq, const float* __restrict__ Wk,
                            const float* __restrict__ Wv, const float* __restrict__ Wo,
                            const float* __restrict__ W1, const float* __restrict__ W2,
                            u16* __restrict__ o) {
  int i = blockIdx.x * 256 + threadIdx.x;
  if (i >= 196608) return;
  float v;
  if (i < 49152) {
    int which = i >> 14, j = i & 16383;
    int n = j >> 7, k = j & 127;
    const float* W = (which == 0) ? Wq : (which == 1) ? Wk : Wv;
    v = W[((n >> 4) * 128 + k) * 16 + (n & 15)];
  } else if (i < 65536) {
    int j = i - 49152;
    v = Wo[(j & 127) * 128 + (j >> 7)];
  } else if (i < 131072) {
    int j = i - 65536;
    v = W1[(j & 127) * 512 + (j >> 7)];
  } else {
    int j = i - 131072;
    int c = j & 127, r = (j >> 7) & 15, nt = (j >> 11) & 7, cc = j >> 14;
    v = W2[(cc * 128 + c) * 128 + nt * 16 + r];
  }
  o[i] = f2b(v);
}

// LayerNorm from regs in MFMA C-layout: v[nt][rg] = x[r0+rg][nt*16+l15].
__device__ __forceinline__ void ln_regs(const float (&v)[8][4], const float* __restrict__ g,
                                        const float* __restrict__ be,
                                        u16* __restrict__ dst, int r0, int l15) {
  #pragma unroll
  for (int rg = 0; rg < 4; ++rg) {
    float s = 0.f;
    #pragma unroll
    for (int nt = 0; nt < 8; ++nt) s += v[nt][rg];
    s += __shfl_xor(s, 1); s += __shfl_xor(s, 2);
    s += __shfl_xor(s, 4); s += __shfl_xor(s, 8);
    float mu = s * 0.0078125f;
    float vv = 0.f;
    #pragma unroll
    for (int nt = 0; nt < 8; ++nt) { float d = v[nt][rg] - mu; vv += d * d; }
    vv += __shfl_xor(vv, 1); vv += __shfl_xor(vv, 2);
    vv += __shfl_xor(vv, 4); vv += __shfl_xor(vv, 8);
    float rs = rsqrtf(vv * 0.0078125f + 1e-5f);
    #pragma unroll
    for (int nt = 0; nt < 8; ++nt) {
      int col = nt * 16 + l15;
      dst[(r0 + rg) * LDA + col] = f2b((v[nt][rg] - mu) * rs * g[col] + be[col]);
    }
  }
}

// ---------------- fused transformer block, col-split weight GEMMs -------------
// 2 LDS buffers (69.6 KB -> 2 blocks/CU). Wave w owns output cols w*16..+15 in
// every weight GEMM (weight frags loaded once per block, reused over 8 row
// tiles) and head w in attention.
__global__ void __launch_bounds__(512, 4)
tblock_kernel(const float* __restrict__ xg, const u16* __restrict__ wts,
              const float* __restrict__ bo, const float* __restrict__ b1,
              const float* __restrict__ b2, const float* __restrict__ g1,
              const float* __restrict__ be1, const float* __restrict__ g2,
              const float* __restrict__ be2, float* __restrict__ out) {
  extern __shared__ u16 sm[];
  u16* buf1 = sm;                // h -> x1(bf16) -> h2(in-place)
  u16* buf2 = sm + 128 * LDA;    // K -> Q -> O(in-place) -> relu chunks

  const int tid  = threadIdx.x;
  const int w    = tid >> 6;
  const int lane = tid & 63;
  const int l15  = lane & 15;
  const int lg   = lane >> 4;
  const int r0   = w * 16 + lg * 4;

  const u16* WqT = wts;
  const u16* WkT = wts + 16384;
  const u16* WvT = wts + 32768;
  const u16* WoT = wts + 49152;
  const u16* W1T = wts + 65536;
  const u16* W2S = wts + 131072;

  const float* xp = xg + (size_t)blockIdx.x * 16384;
  float*       op = out + (size_t)blockIdx.x * 16384;

  const f32x4 zf4 = {0.f, 0.f, 0.f, 0.f};
  const bf16x8 zb8 = zero8();

  // ---- LN1: x -> h into buf1 (row-split)
  {
    float xr[8][4];
    #pragma unroll
    for (int nt = 0; nt < 8; ++nt)
      #pragma unroll
      for (int rg = 0; rg < 4; ++rg)
        xr[nt][rg] = xp[(r0 + rg) * 128 + nt * 16 + l15];
    ln_regs(xr, g1, be1, buf1, r0, l15);
  }
  __syncthreads();   // [bar] h visible to all (cross-wave A-reads below)

  // ---- V GEMM (col-split: wave w computes V[:, head w]) -> av[4] via shuffles
  bf16x8 av[4];
  {
    bf16x8 bw[4];
    #pragma unroll
    for (int kk = 0; kk < 4; ++kk)
      bw[kk] = *(const bf16x8*)(WvT + (w * 16 + l15) * 128 + kk * 32 + lg * 8);
    f32x4 va[8];
    #pragma unroll
    for (int mt = 0; mt < 8; ++mt) {
      va[mt] = zf4;
      #pragma unroll
      for (int kk = 0; kk < 4; ++kk)
        va[mt] = mfma16(*(const bf16x8*)(buf1 + (mt * 16 + l15) * LDA + kk * 32 + lg * 8),
                        bw[kk], va[mt]);
    }
    // av[kk] (A-frag of V^T): lane (l15,lg) = V[t=kk*32+lg*8+j][w*16+l15]
    #pragma unroll
    for (int kk = 0; kk < 4; ++kk)
      av[kk] = gatherB(va[2 * kk], va[2 * kk + 1], true, 1.f, l15, lg);
  }

  // ---- K GEMM -> buf2 as K[t][e] -> bk[8] regs
  bf16x8 bk[8];
  {
    bf16x8 bw[4];
    #pragma unroll
    for (int kk = 0; kk < 4; ++kk)
      bw[kk] = *(const bf16x8*)(WkT + (w * 16 + l15) * 128 + kk * 32 + lg * 8);
    f32x4 ka[8];
    #pragma unroll
    for (int mt = 0; mt < 8; ++mt) {
      ka[mt] = zf4;
      #pragma unroll
      for (int kk = 0; kk < 4; ++kk)
        ka[mt] = mfma16(*(const bf16x8*)(buf1 + (mt * 16 + l15) * LDA + kk * 32 + lg * 8),
                        bw[kk], ka[mt]);
    }
    #pragma unroll
    for (int mt = 0; mt < 8; ++mt)
      #pragma unroll
      for (int rg = 0; rg < 4; ++rg)
        buf2[(mt * 16 + lg * 4 + rg) * LDA + w * 16 + l15] = f2b(ka[mt][rg]);
  }
  __syncthreads();   // [bar] K[t][e] complete
  #pragma unroll
  for (int st = 0; st < 8; ++st) {
    bk[st] = zb8;
    if (lg < 2) bk[st] = *(const bf16x8*)(buf2 + (st * 16 + l15) * LDA + w * 16 + lg * 8);
  }
  __syncthreads();   // [bar] K reads done, buf2 reusable

  // ---- Q GEMM -> buf2 as Q[t][e] (resident through attention)
  {
    bf16x8 bw[4];
    #pragma unroll
    for (int kk = 0; kk < 4; ++kk)
      bw[kk] = *(const bf16x8*)(WqT + (w * 16 + l15) * 128 + kk * 32 + lg * 8);
    f32x4 qa[8];
    #pragma unroll
    for (int mt = 0; mt < 8; ++mt) {
      qa[mt] = zf4;
      #pragma unroll
      for (int kk = 0; kk < 4; ++kk)
        qa[mt] = mfma16(*(const bf16x8*)(buf1 + (mt * 16 + l15) * LDA + kk * 32 + lg * 8),
                        bw[kk], qa[mt]);
    }
    #pragma unroll
    for (int mt = 0; mt < 8; ++mt)
      #pragma unroll
      for (int rg = 0; rg < 4; ++rg)
        buf2[(mt * 16 + lg * 4 + rg) * LDA + w * 16 + l15] = f2b(qa[mt][rg]);
  }
  __syncthreads();   // [bar] Q visible; h (buf1) now dead

  // ---- attention: wave w = head w. S^T = mfma(K,Q); lane owns q-row t=mt*16+l15.
  #pragma unroll 1
  for (int mt = 0; mt < 8; ++mt) {
    bf16x8 aq = zb8;
    if (lg < 2) aq = *(const bf16x8*)(buf2 + (mt * 16 + l15) * LDA + w * 16 + lg * 8);

    f32x4 sacc[8];
    #pragma unroll
    for (int st = 0; st < 8; ++st)
      sacc[st] = (st <= mt) ? mfma16(bk[st], aq, zf4) : zf4;

    float mx = -3.0e38f;
    #pragma unroll
    for (int st = 0; st < 8; ++st) if (st <= mt) {
      #pragma unroll
      for (int rg = 0; rg < 4; ++rg) {
        float sv = sacc[st][rg] * 0.25f;
        bool ok = (st < mt) || ((lg * 4 + rg) <= l15);
        sv = ok ? sv : -1.0e30f;
        sacc[st][rg] = sv;
        mx = fmaxf(mx, sv);
      }
    }
    mx = fmaxf(mx, __shfl_xor(mx, 16));
    mx = fmaxf(mx, __shfl_xor(mx, 32));
    float sum = 0.f;
    #pragma unroll
    for (int st = 0; st < 8; ++st) if (st <= mt) {
      #pragma unroll
      for (int rg = 0; rg < 4; ++rg) {
        float e = __expf(sacc[st][rg] - mx);
        sacc[st][rg] = e;
        sum += e;
      }
    }
    sum += __shfl_xor(sum, 16);
    sum += __shfl_xor(sum, 32);
    float inv = 1.f / sum;

    f32x4 oacc = zf4;
    #pragma unroll
    for (int kk = 0; kk < 4; ++kk) if (kk <= (mt >> 1)) {
      bf16x8 fr = gatherB(sacc[2 * kk], sacc[2 * kk + 1], (2 * kk + 1) <= mt, inv, l15, lg);
      oacc = mfma16(av[kk], fr, oacc);   // O^T frag: row=e_local, col=t_local
    }
    union { u16 h[4]; ushort4 s4; } ow;
    #pragma unroll
    for (int rg = 0; rg < 4; ++rg) ow.h[rg] = f2b(oacc[rg]);
    // O[t][e] over the just-consumed Q stripe (same wave, same 16-col region)
    *(ushort4*)(buf2 + (mt * 16 + l15) * LDA + w * 16 + lg * 4) = ow.s4;
  }
  __syncthreads();   // [bar] O[t][e] complete

  // ---- Wo GEMM (col-split) + residual; x1 -> d_out (f32) and buf1 (bf16)
  {
    bf16x8 bw[4];
    #pragma unroll
    for (int kk = 0; kk < 4; ++kk)
      bw[kk] = *(const bf16x8*)(WoT + (w * 16 + l15) * 128 + kk * 32 + lg * 8);
    float bov = bo[w * 16 + l15];
    #pragma unroll
    for (int mt = 0; mt < 8; ++mt) {
      float xrl[4];
      #pragma unroll
      for (int rg = 0; rg < 4; ++rg)
        xrl[rg] = xp[(mt * 16 + lg * 4 + rg) * 128 + w * 16 + l15];
      f32x4 acc = zf4;
      #pragma unroll
      for (int kk = 0; kk < 4; ++kk)
        acc = mfma16(*(const bf16x8*)(buf2 + (mt * 16 + l15) * LDA + kk * 32 + lg * 8),
                     bw[kk], acc);
      #pragma unroll
      for (int rg = 0; rg < 4; ++rg) {
        float x1v = acc[rg] + bov + xrl[rg];
        int row = mt * 16 + lg * 4 + rg;
        op[row * 128 + w * 16 + l15] = x1v;                  // park x1 fp32 in d_out
        buf1[row * LDA + w * 16 + l15] = f2b(x1v);           // x1 bf16 for LN2
      }
    }
  }
  __syncthreads();   // [bar] x1(bf16) complete in buf1

  // ---- LN2 in-place on buf1 (row-split: 4 lanes per row)
  {
    int rw  = w * 16 + (lane >> 2);
    int sub = lane & 3;
    u16* rp = buf1 + rw * LDA;
    float tv[32];
    float s = 0.f;
    #pragma unroll
    for (int j = 0; j < 32; ++j) { tv[j] = b2f(rp[sub + 4 * j]); s += tv[j]; }
    s += __shfl_xor(s, 1); s += __shfl_xor(s, 2);
    float mu = s * 0.0078125f;
    float vv = 0.f;
    #pragma unroll
    for (int j = 0; j < 32; ++j) { float d = tv[j] - mu; vv += d * d; }
    vv += __shfl_xor(vv, 1); vv += __shfl_xor(vv, 2);
    float rs = rsqrtf(vv * 0.0078125f + 1e-5f);
    #pragma unroll
    for (int j = 0; j < 32; ++j) {
      int c = sub + 4 * j;
      rp[c] = f2b((tv[j] - mu) * rs * g2[c] + be2[c]);
    }
  }
  __syncthreads();   // [bar] h2 visible

  // ---- FFN (col-split): per cc: W1 tile w -> relu chunk in buf2 -> W2 partial
  {
    f32x4 oacc2[8];
    #pragma unroll
    for (int mt = 0; mt < 8; ++mt) oacc2[mt] = zf4;

    #pragma unroll 1
    for (int cc = 0; cc < 4; ++cc) {
      bf16x8 bw1[4];
      #pragma unroll
      for (int kk = 0; kk < 4; ++kk)
        bw1[kk] = *(const bf16x8*)(W1T + (cc * 128 + w * 16 + l15) * 128 + kk * 32 + lg * 8);
      float b1v = b1[cc * 128 + w * 16 + l15];
      #pragma unroll
      for (int mt = 0; mt < 8; ++mt) {
        f32x4 facc = zf4;
        #pragma unroll
        for (int kk = 0; kk < 4; ++kk)
          facc = mfma16(*(const bf16x8*)(buf1 + (mt * 16 + l15) * LDA + kk * 32 + lg * 8),
                        bw1[kk], facc);
        #pragma unroll
        for (int rg = 0; rg < 4; ++rg)
          buf2[(mt * 16 + lg * 4 + rg) * LDA + w * 16 + l15] =
              f2b(fmaxf(facc[rg] + b1v, 0.f));
      }
      __syncthreads();   // [bar] relu chunk complete

      bf16x8 bw2[4];
      #pragma unroll
      for (int kk = 0; kk < 4; ++kk)
        bw2[kk] = *(const bf16x8*)(W2S + ((cc * 8 + w) * 16 + l15) * 128 + kk * 32 + lg * 8);
      #pragma unroll
      for (int mt = 0; mt < 8; ++mt)
        #pragma unroll
        for (int kk = 0; kk < 4; ++kk)
          oacc2[mt] = mfma16(*(const bf16x8*)(buf2 + (mt * 16 + l15) * LDA + kk * 32 + lg * 8),
                             bw2[kk], oacc2[mt]);
      __syncthreads();   // [bar] relu reads done (next cc overwrites)
    }

    // ---- epilogue: out = oacc2 + b2 + x1 (x1 re-read from d_out, wave-private)
    float b2v = b2[w * 16 + l15];
    #pragma unroll
    for (int mt = 0; mt < 8; ++mt) {
      float x1r[4];
      #pragma unroll
      for (int rg = 0; rg < 4; ++rg)
        x1r[rg] = op[(mt * 16 + lg * 4 + rg) * 128 + w * 16 + l15];
      #pragma unroll
      for (int rg = 0; rg < 4; ++rg)
        op[(mt * 16 + lg * 4 + rg) * 128 + w * 16 + l15] = oacc2[mt][rg] + b2v + x1r[rg];
    }
  }
}

extern "C" void kernel_launch(void* const* d_in, const int* in_sizes, int n_in,
                              void* d_out, int out_size, void* d_ws, size_t ws_size,
                              hipStream_t stream) {
  const float* x   = (const float*)d_in[0];
  const float* Wq  = (const float*)d_in[1];
  const float* Wk  = (const float*)d_in[2];
  const float* Wv  = (const float*)d_in[3];
  const float* Wo  = (const float*)d_in[4];
  const float* bo  = (const float*)d_in[5];
  const float* W1  = (const float*)d_in[6];
  const float* b1  = (const float*)d_in[7];
  const float* W2  = (const float*)d_in[8];
  const float* b2  = (const float*)d_in[9];
  const float* g1  = (const float*)d_in[10];
  const float* be1 = (const float*)d_in[11];
  const float* g2  = (const float*)d_in[12];
  const float* be2 = (const float*)d_in[13];
  u16* wts = (u16*)d_ws;

  prep_kernel<<<768, 256, 0, stream>>>(Wq, Wk, Wv, Wo, W1, W2, wts);

  const int smem_bytes = 2 * 128 * LDA * 2;  // 69632 -> 2 blocks/CU
  hipFuncSetAttribute(reinterpret_cast<const void*>(tblock_kernel),
                      hipFuncAttributeMaxDynamicSharedMemorySize, smem_bytes);
  tblock_kernel<<<1024, 512, smem_bytes, stream>>>(x, wts, bo, b1, b2, g1, be1, g2,
                                                   be2, (float*)d_out);
}